// Round 3
// baseline (977.386 us; speedup 1.0000x reference)
//
#include <hip/hip_runtime.h>

typedef unsigned short u16;
typedef unsigned int u32;
typedef __attribute__((ext_vector_type(8))) short bf16x8;
typedef __attribute__((ext_vector_type(4))) float f32x4;

#define B_ 2
#define L_ 4096
#define HS_ 2048
#define NH_ 16
#define HD_ 128
#define FD_ 256

__device__ __forceinline__ float bf2f(u16 u) { return __uint_as_float(((u32)u) << 16); }
__device__ __forceinline__ u16 f2bf(float f) {
    u32 x = __float_as_uint(f);
    return (u16)((x + 0x7fffu + ((x >> 16) & 1u)) >> 16);
}

// async global->LDS, 16B per lane; LDS dest = wave-uniform base + lane*16
__device__ __forceinline__ void llds16(const u16* g, u16* l) {
    __builtin_amdgcn_global_load_lds((const __attribute__((address_space(1))) void*)g,
                                     (__attribute__((address_space(3))) void*)l, 16, 0, 0);
}

// ---------------------------------------------------------------------------
// Shared MFMA mainloop: C[128x128] block, 4 waves (2x2), 16x16x32 bf16 MFMA.
// A: [M,K] row-major bf16. Bt: [N,K] row-major bf16. LDS tiles [128][32].
// A-frag: A[m=lane&15][k=(lane>>4)*8+j]; D-frag: D[m=(lane>>4)*4+r][n=lane&15]
// ---------------------------------------------------------------------------
__device__ __forceinline__ void gemm_mainloop(const u16* __restrict__ Ab, int lda,
                                              const u16* __restrict__ Bb, int ldb,
                                              int K, u16* As, u16* Bs, f32x4 (&acc)[4][4]) {
    const int tid  = threadIdx.x;
    const int lane = tid & 63;
    const int wave = tid >> 6;
    const int wm = wave >> 1, wn = wave & 1;

    f32x4 zero = {0.f, 0.f, 0.f, 0.f};
#pragma unroll
    for (int i = 0; i < 4; i++)
#pragma unroll
        for (int j = 0; j < 4; j++) acc[i][j] = zero;

    const int srow = lane >> 2;
    const int scol = (lane & 3) * 8;
    const u16* pa = Ab + (size_t)(wave * 32 + srow) * lda + scol;
    const u16* pb = Bb + (size_t)(wave * 32 + srow) * ldb + scol;
    u16* la = As + wave * 1024;
    u16* lb = Bs + wave * 1024;

    const int arow = (wm * 64 + (lane & 15)) * 32 + (lane >> 4) * 8;
    const int brow = (wn * 64 + (lane & 15)) * 32 + (lane >> 4) * 8;

    for (int k0 = 0; k0 < K; k0 += 32) {
        llds16(pa, la);
        llds16(pa + 16 * lda, la + 512);
        llds16(pb, lb);
        llds16(pb + 16 * ldb, lb + 512);
        pa += 32; pb += 32;
        __syncthreads();
        bf16x8 af[4], bg[4];
#pragma unroll
        for (int mt = 0; mt < 4; mt++) af[mt] = *(const bf16x8*)(As + arow + mt * 512);
#pragma unroll
        for (int nt = 0; nt < 4; nt++) bg[nt] = *(const bf16x8*)(Bs + brow + nt * 512);
#pragma unroll
        for (int mt = 0; mt < 4; mt++)
#pragma unroll
            for (int nt = 0; nt < 4; nt++)
                acc[mt][nt] = __builtin_amdgcn_mfma_f32_16x16x32_bf16(af[mt], bg[nt], acc[mt][nt], 0, 0, 0);
        __syncthreads();
    }
}

// ---------------------------------------------------------------------------
// fp32 -> bf16 bulk convert (hidden_states -> Xbf). n multiple of 2048.
// ---------------------------------------------------------------------------
__global__ __launch_bounds__(256) void k_cvt(const float* __restrict__ src, u16* __restrict__ dst) {
    size_t i = ((size_t)blockIdx.x * 256 + threadIdx.x) * 8;
    float4 a = *(const float4*)(src + i);
    float4 b = *(const float4*)(src + i + 4);
    union { u16 h[8]; uint4 v; } o;
    o.h[0] = f2bf(a.x); o.h[1] = f2bf(a.y); o.h[2] = f2bf(a.z); o.h[3] = f2bf(a.w);
    o.h[4] = f2bf(b.x); o.h[5] = f2bf(b.y); o.h[6] = f2bf(b.z); o.h[7] = f2bf(b.w);
    *(uint4*)(dst + i) = o.v;
}

// ---------------------------------------------------------------------------
// Weight transposes + fp32->bf16: W[k][n] fp32 -> Wt[n][k] bf16
// ---------------------------------------------------------------------------
__global__ __launch_bounds__(256) void k_transpose(const float* Wq, const float* Wk, const float* Wv,
                                                   const float* Wo, const float* Wf1, const float* Wf2,
                                                   u16* Wqkv_t, u16* Wo_t, u16* Wf1_t, u16* Wf2_t) {
    const float* src; u16* dst; int R, C;
    switch (blockIdx.z) {
        case 0: src = Wq;  dst = Wqkv_t;                R = 2048; C = 2048; break;
        case 1: src = Wk;  dst = Wqkv_t + 2048 * 2048;  R = 2048; C = 2048; break;
        case 2: src = Wv;  dst = Wqkv_t + 2 * 2048 * 2048; R = 2048; C = 2048; break;
        case 3: src = Wo;  dst = Wo_t;                  R = 2048; C = 2048; break;
        case 4: src = Wf1; dst = Wf1_t;                 R = 128;  C = 256;  break;
        default: src = Wf2; dst = Wf2_t;                R = 256;  C = 256;  break;
    }
    int c0 = blockIdx.x * 32, r0 = blockIdx.y * 32;
    if (c0 >= C || r0 >= R) return;
    __shared__ u16 tile[32][33];
    int tx = threadIdx.x, ty = threadIdx.y;
    for (int i = ty; i < 32; i += 8) tile[i][tx] = f2bf(src[(size_t)(r0 + i) * C + c0 + tx]);
    __syncthreads();
    for (int i = ty; i < 32; i += 8) dst[(size_t)(c0 + i) * R + r0 + tx] = tile[tx][i];
}

// ---------------------------------------------------------------------------
// QKV gemm: Xbf[8192,2048] @ Wqkv_t[6144,2048]^T -> q/k/v [bh*L + l][d] + bias
// ---------------------------------------------------------------------------
__global__ __launch_bounds__(256) void k_gemm_qkv(const u16* __restrict__ X, const u16* __restrict__ Wt,
                                                  const float* __restrict__ bq, const float* __restrict__ bk,
                                                  const float* __restrict__ bv,
                                                  u16* __restrict__ qb, u16* __restrict__ kb, u16* __restrict__ vb) {
    __shared__ u16 As[4096], Bs[4096];
    f32x4 acc[4][4];
    const int mb = blockIdx.x * 128, nb = blockIdx.y * 128;
    gemm_mainloop(X + (size_t)mb * HS_, HS_, Wt + (size_t)nb * HS_, HS_, HS_, As, Bs, acc);
    const int lane = threadIdx.x & 63, wave = threadIdx.x >> 6;
    const int wm = wave >> 1, wn = wave & 1;
    const int n0 = nb + wn * 64 + (lane & 15);
    const int m0 = mb + wm * 64 + ((lane >> 4) << 2);
#pragma unroll
    for (int nt = 0; nt < 4; nt++) {
        int n = n0 + nt * 16;
        int which = n >> 11, col = n & 2047;
        const float* bias = (which == 0) ? bq : (which == 1 ? bk : bv);
        u16* dst = (which == 0) ? qb : (which == 1 ? kb : vb);
        float bvv = bias[col];
        int h = col >> 7, d = col & 127;
#pragma unroll
        for (int mt = 0; mt < 4; mt++) {
#pragma unroll
            for (int r = 0; r < 4; r++) {
                int m = m0 + mt * 16 + r;
                int b = m >> 12, l = m & 4095;
                dst[((size_t)((b * NH_ + h) * L_ + l)) * HD_ + d] = f2bf(acc[mt][nt][r] + bvv);
            }
        }
    }
}

// ---------------------------------------------------------------------------
// Fused feature map: per 64-row tile of x[131072,128]:
//   h1 = relu(x @ Wf1 + b1)  (LDS bf16, ld=264); h2 = h1 @ Wf2 + b2 (same LDS)
//   feat = LN(h2)*g + b  [* (1+mask) if MASKED]
// ---------------------------------------------------------------------------
template <int MASKED>
__global__ __launch_bounds__(256) void k_feat(const u16* __restrict__ X,
                                              const u16* __restrict__ W1t, const float* __restrict__ b1,
                                              const u16* __restrict__ W2t, const float* __restrict__ b2,
                                              const float* __restrict__ g, const float* __restrict__ be,
                                              const float* __restrict__ mask,
                                              u16* __restrict__ feat) {
    __shared__ u16 As[64 * 32];
    __shared__ u16 Bs[256 * 32];
    __shared__ u16 H[64 * 264];
    const int tid = threadIdx.x, lane = tid & 63, wave = tid >> 6;
    const int mb = blockIdx.x * 64;

    const int srow = lane >> 2, scol = (lane & 3) * 8;
    const int arow_rd = (lane & 15);
    const int kgrp = (lane >> 4) * 8;

    f32x4 acc[4][4];
    f32x4 zero = {0.f, 0.f, 0.f, 0.f};
#pragma unroll
    for (int i = 0; i < 4; i++)
#pragma unroll
        for (int j = 0; j < 4; j++) acc[i][j] = zero;

    // ---- GEMM1: x[64,128] @ W1t[256,128]^T ----
    for (int k0 = 0; k0 < 128; k0 += 32) {
        llds16(X + (size_t)(mb + wave * 16 + srow) * 128 + k0 + scol, As + wave * 512);
#pragma unroll
        for (int i = 0; i < 4; i++)
            llds16(W1t + (size_t)((wave * 4 + i) * 16 + srow) * 128 + k0 + scol,
                   Bs + (wave * 4 + i) * 512);
        __syncthreads();
        bf16x8 af[4], bg[4];
#pragma unroll
        for (int mt = 0; mt < 4; mt++) af[mt] = *(const bf16x8*)(As + (mt * 16 + arow_rd) * 32 + kgrp);
#pragma unroll
        for (int nt = 0; nt < 4; nt++) bg[nt] = *(const bf16x8*)(Bs + (wave * 64 + nt * 16 + arow_rd) * 32 + kgrp);
#pragma unroll
        for (int mt = 0; mt < 4; mt++)
#pragma unroll
            for (int nt = 0; nt < 4; nt++)
                acc[mt][nt] = __builtin_amdgcn_mfma_f32_16x16x32_bf16(af[mt], bg[nt], acc[mt][nt], 0, 0, 0);
        __syncthreads();
    }
    {
        const int rbase = (lane >> 4) << 2;
#pragma unroll
        for (int nt = 0; nt < 4; nt++) {
            int n = wave * 64 + nt * 16 + (lane & 15);
            float bvv = b1[n];
#pragma unroll
            for (int mt = 0; mt < 4; mt++)
#pragma unroll
                for (int r = 0; r < 4; r++) {
                    float v = fmaxf(acc[mt][nt][r] + bvv, 0.f);
                    H[(mt * 16 + rbase + r) * 264 + n] = f2bf(v);
                }
            acc[0][nt] = zero; acc[1][nt] = zero; acc[2][nt] = zero; acc[3][nt] = zero;
        }
    }
    __syncthreads();

    // ---- GEMM2: h1[64,256] @ W2t[256,256]^T ----
    for (int k0 = 0; k0 < 256; k0 += 32) {
#pragma unroll
        for (int i = 0; i < 4; i++)
            llds16(W2t + (size_t)((wave * 4 + i) * 16 + srow) * 256 + k0 + scol,
                   Bs + (wave * 4 + i) * 512);
        __syncthreads();
        bf16x8 af[4], bg[4];
#pragma unroll
        for (int mt = 0; mt < 4; mt++) af[mt] = *(const bf16x8*)(H + (mt * 16 + arow_rd) * 264 + k0 + kgrp);
#pragma unroll
        for (int nt = 0; nt < 4; nt++) bg[nt] = *(const bf16x8*)(Bs + (wave * 64 + nt * 16 + arow_rd) * 32 + kgrp);
#pragma unroll
        for (int mt = 0; mt < 4; mt++)
#pragma unroll
            for (int nt = 0; nt < 4; nt++)
                acc[mt][nt] = __builtin_amdgcn_mfma_f32_16x16x32_bf16(af[mt], bg[nt], acc[mt][nt], 0, 0, 0);
        __syncthreads();
    }
    {
        const int rbase = (lane >> 4) << 2;
#pragma unroll
        for (int nt = 0; nt < 4; nt++) {
            int n = wave * 64 + nt * 16 + (lane & 15);
            float bvv = b2[n];
#pragma unroll
            for (int mt = 0; mt < 4; mt++)
#pragma unroll
                for (int r = 0; r < 4; r++)
                    H[(mt * 16 + rbase + r) * 264 + n] = f2bf(acc[mt][nt][r] + bvv);
        }
    }
    __syncthreads();

    // ---- LayerNorm: wave w handles local rows w*16 .. w*16+15 ----
    {
        int j = lane * 4;
        float4 gg = *(const float4*)(g + j);
        float4 bb = *(const float4*)(be + j);
        for (int r = 0; r < 16; r++) {
            int row = wave * 16 + r;
            uint2 u = *(const uint2*)(H + row * 264 + j);
            float x0 = bf2f((u16)(u.x & 0xffff)), x1 = bf2f((u16)(u.x >> 16));
            float x2 = bf2f((u16)(u.y & 0xffff)), x3 = bf2f((u16)(u.y >> 16));
            float s = x0 + x1 + x2 + x3;
            float ss = x0 * x0 + x1 * x1 + x2 * x2 + x3 * x3;
#pragma unroll
            for (int o = 32; o >= 1; o >>= 1) { s += __shfl_xor(s, o); ss += __shfl_xor(ss, o); }
            float mu = s * (1.f / FD_);
            float var = ss * (1.f / FD_) - mu * mu;
            float rstd = rsqrtf(var + 1e-5f);
            float fac = 1.f;
            int grow = mb + row;
            if (MASKED) {
                int b = grow >> 16;
                int l = grow & 4095;
                fac = 1.f + mask[b * L_ + l];
            }
            float y0 = ((x0 - mu) * rstd * gg.x + bb.x) * fac;
            float y1 = ((x1 - mu) * rstd * gg.y + bb.y) * fac;
            float y2 = ((x2 - mu) * rstd * gg.z + bb.z) * fac;
            float y3 = ((x3 - mu) * rstd * gg.w + bb.w) * fac;
            uint2 o2;
            o2.x = (u32)f2bf(y0) | ((u32)f2bf(y1) << 16);
            o2.y = (u32)f2bf(y2) | ((u32)f2bf(y3) << 16);
            *(uint2*)(feat + (size_t)grow * FD_ + j) = o2;
        }
    }
}

// ---------------------------------------------------------------------------
// kv partials: per (l-chunk=512, f-half, bh): kv[f][d] += k_feat[l][f]*v[l][d]
// ---------------------------------------------------------------------------
__global__ __launch_bounds__(256) void k_kv(const u16* __restrict__ kf, const u16* __restrict__ v,
                                            float* __restrict__ kvp, float* __restrict__ ksp) {
    const int chunk = blockIdx.x, fh = blockIdx.y, bh = blockIdx.z;
    const int t = threadIdx.x;
    const int f = fh * 128 + (t >> 1);
    const int dh = (t & 1) * 64;
    const u16* kfp = kf + ((size_t)bh * L_ + chunk * 512) * FD_ + f;
    const u16* vp  = v  + ((size_t)bh * L_ + chunk * 512) * HD_;
    __shared__ float vt[64][128];
    float acc[64];
#pragma unroll
    for (int i = 0; i < 64; i++) acc[i] = 0.f;
    float ks = 0.f;
    for (int l0 = 0; l0 < 512; l0 += 64) {
#pragma unroll
        for (int i = 0; i < 4; i++) {
            int idx = t + i * 256;
            int lrow = idx >> 4, dg = (idx & 15) * 8;
            uint4 u = *(const uint4*)(vp + (size_t)(l0 + lrow) * HD_ + dg);
            float* wv = &vt[lrow][dg];
            wv[0] = bf2f((u16)(u.x & 0xffff)); wv[1] = bf2f((u16)(u.x >> 16));
            wv[2] = bf2f((u16)(u.y & 0xffff)); wv[3] = bf2f((u16)(u.y >> 16));
            wv[4] = bf2f((u16)(u.z & 0xffff)); wv[5] = bf2f((u16)(u.z >> 16));
            wv[6] = bf2f((u16)(u.w & 0xffff)); wv[7] = bf2f((u16)(u.w >> 16));
        }
        __syncthreads();
        for (int l = 0; l < 64; l++) {
            float kv_ = bf2f(kfp[(size_t)(l0 + l) * FD_]);
            if ((t & 1) == 0) ks += kv_;
            const float* vr = &vt[l][dh];
#pragma unroll
            for (int d = 0; d < 64; d += 4) {
                float4 vv = *(const float4*)(vr + d);
                acc[d + 0] += kv_ * vv.x; acc[d + 1] += kv_ * vv.y;
                acc[d + 2] += kv_ * vv.z; acc[d + 3] += kv_ * vv.w;
            }
        }
        __syncthreads();
    }
    float* o = kvp + (((size_t)chunk * 32 + bh) * FD_ + f) * HD_ + dh;
#pragma unroll
    for (int d = 0; d < 64; d += 4) *(float4*)(o + d) = make_float4(acc[d], acc[d + 1], acc[d + 2], acc[d + 3]);
    if ((t & 1) == 0) ksp[((size_t)chunk * 32 + bh) * FD_ + f] = ks;
}

// reduce 8 chunk partials -> kvT[bh][d][f] bf16  +  k_sum[bh][f] fp32
__global__ __launch_bounds__(256) void k_kvred(const float* __restrict__ kvp, const float* __restrict__ ksp,
                                               u16* __restrict__ kvT, float* __restrict__ ksum) {
    const int p = blockIdx.x, bh = blockIdx.y, t = threadIdx.x;
    const int e0 = p * 4096 + t * 16;
    float s[16];
#pragma unroll
    for (int i = 0; i < 16; i++) s[i] = 0.f;
    for (int c = 0; c < 8; c++) {
        const float* src = kvp + ((size_t)(c * 32 + bh)) * 32768 + e0;
#pragma unroll
        for (int i = 0; i < 16; i += 4) {
            float4 vv = *(const float4*)(src + i);
            s[i] += vv.x; s[i + 1] += vv.y; s[i + 2] += vv.z; s[i + 3] += vv.w;
        }
    }
#pragma unroll
    for (int i = 0; i < 16; i++) {
        int e = e0 + i, fq = e >> 7, d = e & 127;
        kvT[((size_t)bh * HD_ + d) * FD_ + fq] = f2bf(s[i]);
    }
    if (p == 0) {
        float ks = 0.f;
        for (int c = 0; c < 8; c++) ks += ksp[((size_t)(c * 32 + bh)) * FD_ + t];
        ksum[(size_t)bh * FD_ + t] = ks;
    }
}

// denom[row] = q_feat[row,:] . k_sum[bh,:]
__global__ __launch_bounds__(256) void k_denom(const u16* __restrict__ qf, const float* __restrict__ ksum,
                                               float* __restrict__ denom) {
    const int lane = threadIdx.x & 63, wave = threadIdx.x >> 6;
    const size_t row = (size_t)blockIdx.x * 4 + wave;
    const int bh = (int)(row >> 12);
    uint2 u = *(const uint2*)(qf + row * FD_ + lane * 4);
    float4 kk = *(const float4*)(ksum + (size_t)bh * FD_ + lane * 4);
    float d = bf2f((u16)(u.x & 0xffff)) * kk.x + bf2f((u16)(u.x >> 16)) * kk.y
            + bf2f((u16)(u.y & 0xffff)) * kk.z + bf2f((u16)(u.y >> 16)) * kk.w;
#pragma unroll
    for (int o = 32; o >= 1; o >>= 1) d += __shfl_xor(d, o);
    if (lane == 0) denom[row] = d;
}

// attn numerator gemm per head + divide + write bf16 [b,l,h*128+d]
__global__ __launch_bounds__(256) void k_gemm_attn(const u16* __restrict__ qf, const u16* __restrict__ kvT,
                                                   const float* __restrict__ denom, u16* __restrict__ attn) {
    __shared__ u16 As[4096], Bs[4096];
    f32x4 acc[4][4];
    const int mb = blockIdx.x * 128;
    const int bh = blockIdx.y;
    gemm_mainloop(qf + ((size_t)bh * L_ + mb) * FD_, FD_, kvT + (size_t)bh * HD_ * FD_, FD_, FD_, As, Bs, acc);
    const int lane = threadIdx.x & 63, wave = threadIdx.x >> 6;
    const int wm = wave >> 1, wn = wave & 1;
    const int b = bh >> 4, h = bh & 15;
    const int n0 = wn * 64 + (lane & 15);
    const int m0 = mb + wm * 64 + ((lane >> 4) << 2);
#pragma unroll
    for (int mt = 0; mt < 4; mt++) {
#pragma unroll
        for (int r = 0; r < 4; r++) {
            int l = m0 + mt * 16 + r;
            float rden = 1.f / (denom[(size_t)bh * L_ + l] + 1e-8f);
            u16* orow = attn + ((size_t)(b * L_ + l) * HS_) + h * HD_;
#pragma unroll
            for (int nt = 0; nt < 4; nt++) orow[n0 + nt * 16] = f2bf(acc[mt][nt][r] * rden);
        }
    }
}

// final projection: attn[8192,2048] @ Wo_t^T + bo -> d_out (fp32)
__global__ __launch_bounds__(256) void k_gemm_out(const u16* __restrict__ A, const u16* __restrict__ Wt,
                                                  const float* __restrict__ bo, float* __restrict__ out) {
    __shared__ u16 As[4096], Bs[4096];
    f32x4 acc[4][4];
    const int mb = blockIdx.x * 128, nb = blockIdx.y * 128;
    gemm_mainloop(A + (size_t)mb * HS_, HS_, Wt + (size_t)nb * HS_, HS_, HS_, As, Bs, acc);
    const int lane = threadIdx.x & 63, wave = threadIdx.x >> 6;
    const int wm = wave >> 1, wn = wave & 1;
    const int n0 = nb + wn * 64 + (lane & 15);
    const int m0 = mb + wm * 64 + ((lane >> 4) << 2);
#pragma unroll
    for (int nt = 0; nt < 4; nt++) {
        int n = n0 + nt * 16;
        float bvv = bo[n];
#pragma unroll
        for (int mt = 0; mt < 4; mt++)
#pragma unroll
            for (int r = 0; r < 4; r++)
                out[(size_t)(m0 + mt * 16 + r) * HS_ + n] = acc[mt][nt][r] + bvv;
    }
}

// ---------------------------------------------------------------------------
// workspace layout (bytes), total ~246 MiB.
//   [0]          qfeat 67,108,864   (front 25,165,824 = Wqkv_t, then
//                                    [25165824, 58720256) = Xbf — both dead
//                                    after k_gemm_qkv, before qfeat written)
//   [67108864]   kfeat 67,108,864
//   [134217728]  qbuf  33,554,432   -> kvp after q-branch feature map
//   [167772160]  kbuf  33,554,432   -> attn after k-branch feature map
//   [201326592]  vbuf  33,554,432
//   [234881024]  Wo_t   8,388,608
//   [243269632]  Wf1_t     65,536
//   [243335168]  Wf2_t    131,072
//   [243466240]  ksp      262,144
//   [243728384]  kvT    2,097,152
//   [245825536]  ksum      32,768
//   [245858304]  denom    524,288   -> end 246,382,592
// ---------------------------------------------------------------------------
extern "C" void kernel_launch(void* const* d_in, const int* in_sizes, int n_in,
                              void* d_out, int out_size, void* d_ws, size_t ws_size,
                              hipStream_t stream) {
    const float* hs  = (const float*)d_in[0];
    const float* msk = (const float*)d_in[1];
    const float* Wq  = (const float*)d_in[2];  const float* bq  = (const float*)d_in[3];
    const float* Wk  = (const float*)d_in[4];  const float* bk  = (const float*)d_in[5];
    const float* Wv  = (const float*)d_in[6];  const float* bv  = (const float*)d_in[7];
    const float* Wo  = (const float*)d_in[8];  const float* bo  = (const float*)d_in[9];
    const float* Wf1 = (const float*)d_in[10]; const float* bf1 = (const float*)d_in[11];
    const float* Wf2 = (const float*)d_in[12]; const float* bf2 = (const float*)d_in[13];
    const float* lng = (const float*)d_in[14]; const float* lnb = (const float*)d_in[15];
    float* out = (float*)d_out;
    char* w = (char*)d_ws;

    u16* qfeat  = (u16*)(w + 0);
    u16* Wqkv_t = (u16*)(w + 0);               // alias: dead before qfeat written
    u16* Xbf    = (u16*)(w + 25165824u);       // alias: dead before qfeat written
    u16* kfeat  = (u16*)(w + 67108864u);
    u16* qbuf   = (u16*)(w + 134217728u);
    float* kvp  = (float*)(w + 134217728u);    // alias: qbuf dead after k_feat<q>
    u16* kbuf   = (u16*)(w + 167772160u);
    u16* attn   = (u16*)(w + 167772160u);      // alias: kbuf dead after k_feat<k>
    u16* vbuf   = (u16*)(w + 201326592u);
    u16* Wo_t   = (u16*)(w + 234881024u);
    u16* Wf1_t  = (u16*)(w + 243269632u);
    u16* Wf2_t  = (u16*)(w + 243335168u);
    float* ksp  = (float*)(w + 243466240u);
    u16* kvT    = (u16*)(w + 243728384u);
    float* ksum = (float*)(w + 245825536u);
    float* denom = (float*)(w + 245858304u);

    k_cvt<<<dim3(8192), 256, 0, stream>>>(hs, Xbf);
    k_transpose<<<dim3(64, 64, 6), dim3(32, 8), 0, stream>>>(Wq, Wk, Wv, Wo, Wf1, Wf2,
                                                             Wqkv_t, Wo_t, Wf1_t, Wf2_t);
    k_gemm_qkv<<<dim3(64, 48), 256, 0, stream>>>(Xbf, Wqkv_t, bq, bk, bv, qbuf, kbuf, vbuf);
    k_feat<0><<<dim3(2048), 256, 0, stream>>>(qbuf, Wf1_t, bf1, Wf2_t, bf2, lng, lnb, msk, qfeat);
    k_feat<1><<<dim3(2048), 256, 0, stream>>>(kbuf, Wf1_t, bf1, Wf2_t, bf2, lng, lnb, msk, kfeat);
    k_kv<<<dim3(8, 2, 32), 256, 0, stream>>>(kfeat, vbuf, kvp, ksp);
    k_kvred<<<dim3(8, 32), 256, 0, stream>>>(kvp, ksp, kvT, ksum);
    k_denom<<<dim3(32768), 256, 0, stream>>>(qfeat, ksum, denom);
    k_gemm_attn<<<dim3(32, 32), 256, 0, stream>>>(qfeat, kvT, denom, attn);
    k_gemm_out<<<dim3(64, 16), 256, 0, stream>>>(attn, Wo_t, bo, out);
}

// Round 4
// 811.453 us; speedup vs baseline: 1.2045x; 1.2045x over previous
//
#include <hip/hip_runtime.h>

typedef unsigned short u16;
typedef unsigned int u32;
typedef __attribute__((ext_vector_type(8))) short bf16x8;
typedef __attribute__((ext_vector_type(4))) float f32x4;

#define B_ 2
#define L_ 4096
#define HS_ 2048
#define NH_ 16
#define HD_ 128
#define FD_ 256

__device__ __forceinline__ float bf2f(u16 u) { return __uint_as_float(((u32)u) << 16); }
__device__ __forceinline__ u16 f2bf(float f) {
    u32 x = __float_as_uint(f);
    return (u16)((x + 0x7fffu + ((x >> 16) & 1u)) >> 16);
}

// async global->LDS, 16B per lane; LDS dest = wave-uniform base + lane*16
__device__ __forceinline__ void llds16(const u16* g, u16* l) {
    __builtin_amdgcn_global_load_lds((const __attribute__((address_space(1))) void*)g,
                                     (__attribute__((address_space(3))) void*)l, 16, 0, 0);
}

// ---------------------------------------------------------------------------
// Shared MFMA mainloop: C[128x128] block, 4 waves (2x2), 16x16x32 bf16 MFMA.
// A: [M,K] row-major bf16. Bt: [N,K] row-major bf16. LDS tiles [128][32].
// A-frag: A[m=lane&15][k=(lane>>4)*8+j]; D-frag: D[m=(lane>>4)*4+r][n=lane&15]
// ---------------------------------------------------------------------------
__device__ __forceinline__ void gemm_mainloop(const u16* __restrict__ Ab, int lda,
                                              const u16* __restrict__ Bb, int ldb,
                                              int K, u16* As, u16* Bs, f32x4 (&acc)[4][4]) {
    const int tid  = threadIdx.x;
    const int lane = tid & 63;
    const int wave = tid >> 6;
    const int wm = wave >> 1, wn = wave & 1;

    f32x4 zero = {0.f, 0.f, 0.f, 0.f};
#pragma unroll
    for (int i = 0; i < 4; i++)
#pragma unroll
        for (int j = 0; j < 4; j++) acc[i][j] = zero;

    const int srow = lane >> 2;
    const int scol = (lane & 3) * 8;
    const u16* pa = Ab + (size_t)(wave * 32 + srow) * lda + scol;
    const u16* pb = Bb + (size_t)(wave * 32 + srow) * ldb + scol;
    u16* la = As + wave * 1024;
    u16* lb = Bs + wave * 1024;

    const int arow = (wm * 64 + (lane & 15)) * 32 + (lane >> 4) * 8;
    const int brow = (wn * 64 + (lane & 15)) * 32 + (lane >> 4) * 8;

    for (int k0 = 0; k0 < K; k0 += 32) {
        llds16(pa, la);
        llds16(pa + 16 * lda, la + 512);
        llds16(pb, lb);
        llds16(pb + 16 * ldb, lb + 512);
        pa += 32; pb += 32;
        __syncthreads();
        bf16x8 af[4], bg[4];
#pragma unroll
        for (int mt = 0; mt < 4; mt++) af[mt] = *(const bf16x8*)(As + arow + mt * 512);
#pragma unroll
        for (int nt = 0; nt < 4; nt++) bg[nt] = *(const bf16x8*)(Bs + brow + nt * 512);
#pragma unroll
        for (int mt = 0; mt < 4; mt++)
#pragma unroll
            for (int nt = 0; nt < 4; nt++)
                acc[mt][nt] = __builtin_amdgcn_mfma_f32_16x16x32_bf16(af[mt], bg[nt], acc[mt][nt], 0, 0, 0);
        __syncthreads();
    }
}

// ---------------------------------------------------------------------------
// fp32 -> bf16 bulk convert (hidden_states -> Xbf). n multiple of 2048.
// ---------------------------------------------------------------------------
__global__ __launch_bounds__(256) void k_cvt(const float* __restrict__ src, u16* __restrict__ dst) {
    size_t i = ((size_t)blockIdx.x * 256 + threadIdx.x) * 8;
    float4 a = *(const float4*)(src + i);
    float4 b = *(const float4*)(src + i + 4);
    union { u16 h[8]; uint4 v; } o;
    o.h[0] = f2bf(a.x); o.h[1] = f2bf(a.y); o.h[2] = f2bf(a.z); o.h[3] = f2bf(a.w);
    o.h[4] = f2bf(b.x); o.h[5] = f2bf(b.y); o.h[6] = f2bf(b.z); o.h[7] = f2bf(b.w);
    *(uint4*)(dst + i) = o.v;
}

// ---------------------------------------------------------------------------
// Weight transposes + fp32->bf16: W[k][n] fp32 -> Wt[n][k] bf16
// ---------------------------------------------------------------------------
__global__ __launch_bounds__(256) void k_transpose(const float* Wq, const float* Wk, const float* Wv,
                                                   const float* Wo, const float* Wf1, const float* Wf2,
                                                   u16* Wqkv_t, u16* Wo_t, u16* Wf1_t, u16* Wf2_t) {
    const float* src; u16* dst; int R, C;
    switch (blockIdx.z) {
        case 0: src = Wq;  dst = Wqkv_t;                R = 2048; C = 2048; break;
        case 1: src = Wk;  dst = Wqkv_t + 2048 * 2048;  R = 2048; C = 2048; break;
        case 2: src = Wv;  dst = Wqkv_t + 2 * 2048 * 2048; R = 2048; C = 2048; break;
        case 3: src = Wo;  dst = Wo_t;                  R = 2048; C = 2048; break;
        case 4: src = Wf1; dst = Wf1_t;                 R = 128;  C = 256;  break;
        default: src = Wf2; dst = Wf2_t;                R = 256;  C = 256;  break;
    }
    int c0 = blockIdx.x * 32, r0 = blockIdx.y * 32;
    if (c0 >= C || r0 >= R) return;
    __shared__ u16 tile[32][33];
    int tx = threadIdx.x, ty = threadIdx.y;
    for (int i = ty; i < 32; i += 8) tile[i][tx] = f2bf(src[(size_t)(r0 + i) * C + c0 + tx]);
    __syncthreads();
    for (int i = ty; i < 32; i += 8) dst[(size_t)(c0 + i) * R + r0 + tx] = tile[tx][i];
}

// ---------------------------------------------------------------------------
// QKV gemm: Xbf[8192,2048] @ Wqkv_t[6144,2048]^T + bias ->
//   q,k : [bh][l][d]  (feature-map GEMM A operands)
//   vT  : [bh][d][l]  (kv-GEMM B operand; 4 consecutive l packed per store)
// ---------------------------------------------------------------------------
__global__ __launch_bounds__(256) void k_gemm_qkv(const u16* __restrict__ X, const u16* __restrict__ Wt,
                                                  const float* __restrict__ bq, const float* __restrict__ bk,
                                                  const float* __restrict__ bv,
                                                  u16* __restrict__ qb, u16* __restrict__ kb, u16* __restrict__ vT) {
    __shared__ u16 As[4096], Bs[4096];
    f32x4 acc[4][4];
    const int mb = blockIdx.x * 128, nb = blockIdx.y * 128;
    gemm_mainloop(X + (size_t)mb * HS_, HS_, Wt + (size_t)nb * HS_, HS_, HS_, As, Bs, acc);
    const int lane = threadIdx.x & 63, wave = threadIdx.x >> 6;
    const int wm = wave >> 1, wn = wave & 1;
    const int n0 = nb + wn * 64 + (lane & 15);
    const int m0 = mb + wm * 64 + ((lane >> 4) << 2);
#pragma unroll
    for (int nt = 0; nt < 4; nt++) {
        int n = n0 + nt * 16;
        int which = n >> 11, col = n & 2047;
        const float* bias = (which == 0) ? bq : (which == 1 ? bk : bv);
        float bvv = bias[col];
        int h = col >> 7, d = col & 127;
        if (which == 2) {
            // vT[((b*NH+h)*HD + d)*L + l], 4 consecutive l per quad
#pragma unroll
            for (int mt = 0; mt < 4; mt++) {
                int m = m0 + mt * 16;
                int b = m >> 12, l = m & 4095;
                union { u16 h4[4]; uint2 v2; } pk;
#pragma unroll
                for (int r = 0; r < 4; r++) pk.h4[r] = f2bf(acc[mt][nt][r] + bvv);
                *(uint2*)(vT + ((size_t)((b * NH_ + h) * HD_ + d)) * L_ + l) = pk.v2;
            }
        } else {
            u16* dst = (which == 0) ? qb : kb;
#pragma unroll
            for (int mt = 0; mt < 4; mt++) {
#pragma unroll
                for (int r = 0; r < 4; r++) {
                    int m = m0 + mt * 16 + r;
                    int b = m >> 12, l = m & 4095;
                    dst[((size_t)((b * NH_ + h) * L_ + l)) * HD_ + d] = f2bf(acc[mt][nt][r] + bvv);
                }
            }
        }
    }
}

// ---------------------------------------------------------------------------
// Fused feature map: per 64-row tile of x[131072,128]:
//   h1 = relu(x @ Wf1 + b1)  (LDS bf16, ld=264); h2 = h1 @ Wf2 + b2 (same LDS)
//   feat = LN(h2)*g + b  [* (1+mask) if MASKED]
// TRANS=0: write feat[row][f] (q branch). TRANS=1: write featT[bh][f][l]
// (k branch, k-contiguous for the kv GEMM; 8 l packed per 16B store).
// ---------------------------------------------------------------------------
template <int MASKED, int TRANS>
__global__ __launch_bounds__(256) void k_feat(const u16* __restrict__ X,
                                              const u16* __restrict__ W1t, const float* __restrict__ b1,
                                              const u16* __restrict__ W2t, const float* __restrict__ b2,
                                              const float* __restrict__ g, const float* __restrict__ be,
                                              const float* __restrict__ mask,
                                              u16* __restrict__ feat) {
    __shared__ u16 As[64 * 32];
    __shared__ u16 Bs[256 * 32];
    __shared__ u16 H[64 * 264];
    __shared__ float MU[64], RS[64], FAC[64];
    const int tid = threadIdx.x, lane = tid & 63, wave = tid >> 6;
    const int mb = blockIdx.x * 64;

    const int srow = lane >> 2, scol = (lane & 3) * 8;
    const int arow_rd = (lane & 15);
    const int kgrp = (lane >> 4) * 8;

    f32x4 acc[4][4];
    f32x4 zero = {0.f, 0.f, 0.f, 0.f};
#pragma unroll
    for (int i = 0; i < 4; i++)
#pragma unroll
        for (int j = 0; j < 4; j++) acc[i][j] = zero;

    // ---- GEMM1: x[64,128] @ W1t[256,128]^T ----
    for (int k0 = 0; k0 < 128; k0 += 32) {
        llds16(X + (size_t)(mb + wave * 16 + srow) * 128 + k0 + scol, As + wave * 512);
#pragma unroll
        for (int i = 0; i < 4; i++)
            llds16(W1t + (size_t)((wave * 4 + i) * 16 + srow) * 128 + k0 + scol,
                   Bs + (wave * 4 + i) * 512);
        __syncthreads();
        bf16x8 af[4], bg[4];
#pragma unroll
        for (int mt = 0; mt < 4; mt++) af[mt] = *(const bf16x8*)(As + (mt * 16 + arow_rd) * 32 + kgrp);
#pragma unroll
        for (int nt = 0; nt < 4; nt++) bg[nt] = *(const bf16x8*)(Bs + (wave * 64 + nt * 16 + arow_rd) * 32 + kgrp);
#pragma unroll
        for (int mt = 0; mt < 4; mt++)
#pragma unroll
            for (int nt = 0; nt < 4; nt++)
                acc[mt][nt] = __builtin_amdgcn_mfma_f32_16x16x32_bf16(af[mt], bg[nt], acc[mt][nt], 0, 0, 0);
        __syncthreads();
    }
    {
        const int rbase = (lane >> 4) << 2;
#pragma unroll
        for (int nt = 0; nt < 4; nt++) {
            int n = wave * 64 + nt * 16 + (lane & 15);
            float bvv = b1[n];
#pragma unroll
            for (int mt = 0; mt < 4; mt++)
#pragma unroll
                for (int r = 0; r < 4; r++) {
                    float v = fmaxf(acc[mt][nt][r] + bvv, 0.f);
                    H[(mt * 16 + rbase + r) * 264 + n] = f2bf(v);
                }
            acc[0][nt] = zero; acc[1][nt] = zero; acc[2][nt] = zero; acc[3][nt] = zero;
        }
    }
    __syncthreads();

    // ---- GEMM2: h1[64,256] @ W2t[256,256]^T ----
    for (int k0 = 0; k0 < 256; k0 += 32) {
#pragma unroll
        for (int i = 0; i < 4; i++)
            llds16(W2t + (size_t)((wave * 4 + i) * 16 + srow) * 256 + k0 + scol,
                   Bs + (wave * 4 + i) * 512);
        __syncthreads();
        bf16x8 af[4], bg[4];
#pragma unroll
        for (int mt = 0; mt < 4; mt++) af[mt] = *(const bf16x8*)(H + (mt * 16 + arow_rd) * 264 + k0 + kgrp);
#pragma unroll
        for (int nt = 0; nt < 4; nt++) bg[nt] = *(const bf16x8*)(Bs + (wave * 64 + nt * 16 + arow_rd) * 32 + kgrp);
#pragma unroll
        for (int mt = 0; mt < 4; mt++)
#pragma unroll
            for (int nt = 0; nt < 4; nt++)
                acc[mt][nt] = __builtin_amdgcn_mfma_f32_16x16x32_bf16(af[mt], bg[nt], acc[mt][nt], 0, 0, 0);
        __syncthreads();
    }
    {
        const int rbase = (lane >> 4) << 2;
#pragma unroll
        for (int nt = 0; nt < 4; nt++) {
            int n = wave * 64 + nt * 16 + (lane & 15);
            float bvv = b2[n];
#pragma unroll
            for (int mt = 0; mt < 4; mt++)
#pragma unroll
                for (int r = 0; r < 4; r++)
                    H[(mt * 16 + rbase + r) * 264 + n] = f2bf(acc[mt][nt][r] + bvv);
        }
    }
    __syncthreads();

    // ---- LayerNorm stats: wave w reduces rows w*16 .. w*16+15 ----
    {
        for (int r = 0; r < 16; r++) {
            int row = wave * 16 + r;
            int j = lane * 4;
            uint2 u = *(const uint2*)(H + row * 264 + j);
            float x0 = bf2f((u16)(u.x & 0xffff)), x1 = bf2f((u16)(u.x >> 16));
            float x2 = bf2f((u16)(u.y & 0xffff)), x3 = bf2f((u16)(u.y >> 16));
            float s = x0 + x1 + x2 + x3;
            float ss = x0 * x0 + x1 * x1 + x2 * x2 + x3 * x3;
#pragma unroll
            for (int o = 32; o >= 1; o >>= 1) { s += __shfl_xor(s, o); ss += __shfl_xor(ss, o); }
            if (lane == 0) {
                float mu = s * (1.f / FD_);
                float var = ss * (1.f / FD_) - mu * mu;
                MU[row] = mu;
                RS[row] = rsqrtf(var + 1e-5f);
                float fac = 1.f;
                if (MASKED) {
                    int grow = mb + row;
                    int b = grow >> 16;
                    int l = grow & 4095;
                    fac = 1.f + mask[b * L_ + l];
                }
                FAC[row] = fac;
            }
        }
    }
    __syncthreads();

    if (!TRANS) {
        // write feat[row][f], lane covers 4 f, wave rows w*16..+15
        int j = lane * 4;
        float4 gg = *(const float4*)(g + j);
        float4 bb = *(const float4*)(be + j);
        for (int r = 0; r < 16; r++) {
            int row = wave * 16 + r;
            float mu = MU[row], rstd = RS[row], fac = FAC[row];
            uint2 u = *(const uint2*)(H + row * 264 + j);
            float x0 = bf2f((u16)(u.x & 0xffff)), x1 = bf2f((u16)(u.x >> 16));
            float x2 = bf2f((u16)(u.y & 0xffff)), x3 = bf2f((u16)(u.y >> 16));
            uint2 o2;
            o2.x = (u32)f2bf(((x0 - mu) * rstd * gg.x + bb.x) * fac) |
                   ((u32)f2bf(((x1 - mu) * rstd * gg.y + bb.y) * fac) << 16);
            o2.y = (u32)f2bf(((x2 - mu) * rstd * gg.z + bb.z) * fac) |
                   ((u32)f2bf(((x3 - mu) * rstd * gg.w + bb.w) * fac) << 16);
            *(uint2*)(feat + (size_t)(mb + row) * FD_ + j) = o2;
        }
    } else {
        // write featT[bh][f][l]: thread t = f, pack 8 l per 16B store
        int f = tid;
        int bh = mb >> 12, lb = mb & 4095;
        float gf = g[f], bf = be[f];
        u16* orow = feat + ((size_t)bh * FD_ + f) * L_ + lb;
        for (int lg = 0; lg < 64; lg += 8) {
            union { u16 h8[8]; uint4 v4; } pk;
#pragma unroll
            for (int j = 0; j < 8; j++) {
                int row = lg + j;
                float x = bf2f(H[row * 264 + f]);
                pk.h8[j] = f2bf(((x - MU[row]) * RS[row] * gf + bf) * FAC[row]);
            }
            *(uint4*)(orow + lg) = pk.v4;
        }
    }
}

// ---------------------------------------------------------------------------
// ksum[bh][f] = sum_l kfT[bh][f][l]   (one block per row, coalesced)
// ---------------------------------------------------------------------------
__global__ __launch_bounds__(256) void k_ksum(const u16* __restrict__ kfT, float* __restrict__ ksum) {
    const int row = blockIdx.x;   // bh*FD + f, 8192 rows
    const int t = threadIdx.x, lane = t & 63, wave = t >> 6;
    const u16* p = kfT + (size_t)row * L_ + t * 16;
    uint4 a = *(const uint4*)p;
    uint4 b = *(const uint4*)(p + 8);
    float s = 0.f;
    const u32* w32 = (const u32*)&a;
#pragma unroll
    for (int i = 0; i < 4; i++) { s += bf2f((u16)(w32[i] & 0xffff)) + bf2f((u16)(w32[i] >> 16)); }
    const u32* w32b = (const u32*)&b;
#pragma unroll
    for (int i = 0; i < 4; i++) { s += bf2f((u16)(w32b[i] & 0xffff)) + bf2f((u16)(w32b[i] >> 16)); }
#pragma unroll
    for (int o = 32; o >= 1; o >>= 1) s += __shfl_xor(s, o);
    __shared__ float red[4];
    if (lane == 0) red[wave] = s;
    __syncthreads();
    if (t == 0) ksum[row] = red[0] + red[1] + red[2] + red[3];
}

// ---------------------------------------------------------------------------
// kv GEMM: per (f-block, k-slice, bh): kfT[256,4096] @ vT[128,4096]^T
// fp32 partials [ks*32+bh][f][d]
// ---------------------------------------------------------------------------
__global__ __launch_bounds__(256) void k_gemm_kv(const u16* __restrict__ kfT, const u16* __restrict__ vT,
                                                 float* __restrict__ kvp) {
    __shared__ u16 As[4096], Bs[4096];
    f32x4 acc[4][4];
    const int mb = blockIdx.x * 128;    // f block (0..1)
    const int ks = blockIdx.y;          // k slice (0..3), 1024 each
    const int bh = blockIdx.z;
    gemm_mainloop(kfT + ((size_t)bh * FD_ + mb) * L_ + ks * 1024, L_,
                  vT + (size_t)bh * HD_ * L_ + ks * 1024, L_, 1024, As, Bs, acc);
    const int lane = threadIdx.x & 63, wave = threadIdx.x >> 6;
    const int wm = wave >> 1, wn = wave & 1;
    const int n0 = wn * 64 + (lane & 15);
    const int m0 = mb + wm * 64 + ((lane >> 4) << 2);
    float* o = kvp + (size_t)(ks * 32 + bh) * (FD_ * HD_);
#pragma unroll
    for (int nt = 0; nt < 4; nt++)
#pragma unroll
        for (int mt = 0; mt < 4; mt++)
#pragma unroll
            for (int r = 0; r < 4; r++)
                o[(size_t)(m0 + mt * 16 + r) * HD_ + n0 + nt * 16] = acc[mt][nt][r];
}

// reduce 4 k-slice partials -> kvT[bh][d][f] bf16
__global__ __launch_bounds__(256) void k_kvred(const float* __restrict__ kvp, u16* __restrict__ kvT) {
    const int p = blockIdx.x, bh = blockIdx.y, t = threadIdx.x;
    const int e0 = p * 4096 + t * 16;
    float s[16];
#pragma unroll
    for (int i = 0; i < 16; i++) s[i] = 0.f;
    for (int c = 0; c < 4; c++) {
        const float* src = kvp + ((size_t)(c * 32 + bh)) * 32768 + e0;
#pragma unroll
        for (int i = 0; i < 16; i += 4) {
            float4 vv = *(const float4*)(src + i);
            s[i] += vv.x; s[i + 1] += vv.y; s[i + 2] += vv.z; s[i + 3] += vv.w;
        }
    }
#pragma unroll
    for (int i = 0; i < 16; i++) {
        int e = e0 + i, fq = e >> 7, d = e & 127;
        kvT[((size_t)bh * HD_ + d) * FD_ + fq] = f2bf(s[i]);
    }
}

// denom[row] = q_feat[row,:] . k_sum[bh,:]
__global__ __launch_bounds__(256) void k_denom(const u16* __restrict__ qf, const float* __restrict__ ksum,
                                               float* __restrict__ denom) {
    const int lane = threadIdx.x & 63, wave = threadIdx.x >> 6;
    const size_t row = (size_t)blockIdx.x * 4 + wave;
    const int bh = (int)(row >> 12);
    uint2 u = *(const uint2*)(qf + row * FD_ + lane * 4);
    float4 kk = *(const float4*)(ksum + (size_t)bh * FD_ + lane * 4);
    float d = bf2f((u16)(u.x & 0xffff)) * kk.x + bf2f((u16)(u.x >> 16)) * kk.y
            + bf2f((u16)(u.y & 0xffff)) * kk.z + bf2f((u16)(u.y >> 16)) * kk.w;
#pragma unroll
    for (int o = 32; o >= 1; o >>= 1) d += __shfl_xor(d, o);
    if (lane == 0) denom[row] = d;
}

// attn numerator gemm per head + divide + write bf16 [b,l,h*128+d]
__global__ __launch_bounds__(256) void k_gemm_attn(const u16* __restrict__ qf, const u16* __restrict__ kvT,
                                                   const float* __restrict__ denom, u16* __restrict__ attn) {
    __shared__ u16 As[4096], Bs[4096];
    f32x4 acc[4][4];
    const int mb = blockIdx.x * 128;
    const int bh = blockIdx.y;
    gemm_mainloop(qf + ((size_t)bh * L_ + mb) * FD_, FD_, kvT + (size_t)bh * HD_ * FD_, FD_, FD_, As, Bs, acc);
    const int lane = threadIdx.x & 63, wave = threadIdx.x >> 6;
    const int wm = wave >> 1, wn = wave & 1;
    const int b = bh >> 4, h = bh & 15;
    const int n0 = wn * 64 + (lane & 15);
    const int m0 = mb + wm * 64 + ((lane >> 4) << 2);
#pragma unroll
    for (int mt = 0; mt < 4; mt++) {
#pragma unroll
        for (int r = 0; r < 4; r++) {
            int l = m0 + mt * 16 + r;
            float rden = 1.f / (denom[(size_t)bh * L_ + l] + 1e-8f);
            u16* orow = attn + ((size_t)(b * L_ + l) * HS_) + h * HD_;
#pragma unroll
            for (int nt = 0; nt < 4; nt++) orow[n0 + nt * 16] = f2bf(acc[mt][nt][r] * rden);
        }
    }
}

// final projection: attn[8192,2048] @ Wo_t^T + bo -> d_out (fp32)
__global__ __launch_bounds__(256) void k_gemm_out(const u16* __restrict__ A, const u16* __restrict__ Wt,
                                                  const float* __restrict__ bo, float* __restrict__ out) {
    __shared__ u16 As[4096], Bs[4096];
    f32x4 acc[4][4];
    const int mb = blockIdx.x * 128, nb = blockIdx.y * 128;
    gemm_mainloop(A + (size_t)mb * HS_, HS_, Wt + (size_t)nb * HS_, HS_, HS_, As, Bs, acc);
    const int lane = threadIdx.x & 63, wave = threadIdx.x >> 6;
    const int wm = wave >> 1, wn = wave & 1;
    const int n0 = nb + wn * 64 + (lane & 15);
    const int m0 = mb + wm * 64 + ((lane >> 4) << 2);
#pragma unroll
    for (int nt = 0; nt < 4; nt++) {
        int n = n0 + nt * 16;
        float bvv = bo[n];
#pragma unroll
        for (int mt = 0; mt < 4; mt++)
#pragma unroll
            for (int r = 0; r < 4; r++)
                out[(size_t)(m0 + mt * 16 + r) * HS_ + n] = acc[mt][nt][r] + bvv;
    }
}

// ---------------------------------------------------------------------------
// workspace layout (bytes), total ~246 MiB.
//   [0]          qfeat 67,108,864   (front: Wqkv_t 25,165,824 then Xbf
//                                    33,554,432 — both dead before qfeat)
//   [67108864]   kfT   67,108,864   ([bh][f][l])
//   [134217728]  qbuf  33,554,432   -> kvp (16 MB fp32 partials) after feat<q>
//   [167772160]  kbuf  33,554,432   -> attn after feat<k>
//   [201326592]  vT    33,554,432   ([bh][d][l])
//   [234881024]  Wo_t   8,388,608
//   [243269632]  Wf1_t     65,536
//   [243335168]  Wf2_t    131,072
//   [243728384]  kvT    2,097,152
//   [245825536]  ksum      32,768
//   [245858304]  denom    524,288   -> end 246,382,592
// ---------------------------------------------------------------------------
extern "C" void kernel_launch(void* const* d_in, const int* in_sizes, int n_in,
                              void* d_out, int out_size, void* d_ws, size_t ws_size,
                              hipStream_t stream) {
    const float* hs  = (const float*)d_in[0];
    const float* msk = (const float*)d_in[1];
    const float* Wq  = (const float*)d_in[2];  const float* bq  = (const float*)d_in[3];
    const float* Wk  = (const float*)d_in[4];  const float* bk  = (const float*)d_in[5];
    const float* Wv  = (const float*)d_in[6];  const float* bv  = (const float*)d_in[7];
    const float* Wo  = (const float*)d_in[8];  const float* bo  = (const float*)d_in[9];
    const float* Wf1 = (const float*)d_in[10]; const float* bf1 = (const float*)d_in[11];
    const float* Wf2 = (const float*)d_in[12]; const float* bf2 = (const float*)d_in[13];
    const float* lng = (const float*)d_in[14]; const float* lnb = (const float*)d_in[15];
    float* out = (float*)d_out;
    char* w = (char*)d_ws;

    u16* qfeat  = (u16*)(w + 0);
    u16* Wqkv_t = (u16*)(w + 0);               // alias: dead before qfeat written
    u16* Xbf    = (u16*)(w + 25165824u);       // alias: dead before qfeat written
    u16* kfT    = (u16*)(w + 67108864u);
    u16* qbuf   = (u16*)(w + 134217728u);
    float* kvp  = (float*)(w + 134217728u);    // alias: qbuf dead after k_feat<q>
    u16* kbuf   = (u16*)(w + 167772160u);
    u16* attn   = (u16*)(w + 167772160u);      // alias: kbuf dead after k_feat<k>
    u16* vT     = (u16*)(w + 201326592u);
    u16* Wo_t   = (u16*)(w + 234881024u);
    u16* Wf1_t  = (u16*)(w + 243269632u);
    u16* Wf2_t  = (u16*)(w + 243335168u);
    u16* kvT    = (u16*)(w + 243728384u);
    float* ksum = (float*)(w + 245825536u);
    float* denom = (float*)(w + 245858304u);

    k_cvt<<<dim3(8192), 256, 0, stream>>>(hs, Xbf);
    k_transpose<<<dim3(64, 64, 6), dim3(32, 8), 0, stream>>>(Wq, Wk, Wv, Wo, Wf1, Wf2,
                                                             Wqkv_t, Wo_t, Wf1_t, Wf2_t);
    k_gemm_qkv<<<dim3(64, 48), 256, 0, stream>>>(Xbf, Wqkv_t, bq, bk, bv, qbuf, kbuf, vT);
    k_feat<0, 0><<<dim3(2048), 256, 0, stream>>>(qbuf, Wf1_t, bf1, Wf2_t, bf2, lng, lnb, msk, qfeat);
    k_feat<1, 1><<<dim3(2048), 256, 0, stream>>>(kbuf, Wf1_t, bf1, Wf2_t, bf2, lng, lnb, msk, kfT);
    k_ksum<<<dim3(8192), 256, 0, stream>>>(kfT, ksum);
    k_gemm_kv<<<dim3(2, 4, 32), 256, 0, stream>>>(kfT, vT, kvp);
    k_kvred<<<dim3(8, 32), 256, 0, stream>>>(kvp, kvT);
    k_denom<<<dim3(32768), 256, 0, stream>>>(qfeat, ksum, denom);
    k_gemm_attn<<<dim3(32, 32), 256, 0, stream>>>(qfeat, kvT, denom, attn);
    k_gemm_out<<<dim3(64, 16), 256, 0, stream>>>(attn, Wo_t, bo, out);
}

// Round 5
// 807.144 us; speedup vs baseline: 1.2109x; 1.0053x over previous
//
#include <hip/hip_runtime.h>

typedef unsigned short u16;
typedef unsigned int u32;
typedef __attribute__((ext_vector_type(8))) short bf16x8;
typedef __attribute__((ext_vector_type(4))) float f32x4;

#define B_ 2
#define L_ 4096
#define HS_ 2048
#define NH_ 16
#define HD_ 128
#define FD_ 256

__device__ __forceinline__ float bf2f(u16 u) { return __uint_as_float(((u32)u) << 16); }
__device__ __forceinline__ u16 f2bf(float f) {
    u32 x = __float_as_uint(f);
    return (u16)((x + 0x7fffu + ((x >> 16) & 1u)) >> 16);
}

// async global->LDS, 16B per lane; LDS dest = wave-uniform base + lane*16
__device__ __forceinline__ void llds16(const u16* g, u16* l) {
    __builtin_amdgcn_global_load_lds((const __attribute__((address_space(1))) void*)g,
                                     (__attribute__((address_space(3))) void*)l, 16, 0, 0);
}

// ---------------------------------------------------------------------------
// Shared MFMA mainloop: C[128x128] block, 4 waves (2x2), 16x16x32 bf16 MFMA.
// A: [M,K] row-major bf16. Bt: [N,K] row-major bf16. LDS tiles [128][32].
// A-frag: A[m=lane&15][k=(lane>>4)*8+j]; D-frag: D[m=(lane>>4)*4+r][n=lane&15]
// ---------------------------------------------------------------------------
__device__ __forceinline__ void gemm_mainloop(const u16* __restrict__ Ab, int lda,
                                              const u16* __restrict__ Bb, int ldb,
                                              int K, u16* As, u16* Bs, f32x4 (&acc)[4][4]) {
    const int tid  = threadIdx.x;
    const int lane = tid & 63;
    const int wave = tid >> 6;
    const int wm = wave >> 1, wn = wave & 1;

    f32x4 zero = {0.f, 0.f, 0.f, 0.f};
#pragma unroll
    for (int i = 0; i < 4; i++)
#pragma unroll
        for (int j = 0; j < 4; j++) acc[i][j] = zero;

    const int srow = lane >> 2;
    const int scol = (lane & 3) * 8;
    const u16* pa = Ab + (size_t)(wave * 32 + srow) * lda + scol;
    const u16* pb = Bb + (size_t)(wave * 32 + srow) * ldb + scol;
    u16* la = As + wave * 1024;
    u16* lb = Bs + wave * 1024;

    const int arow = (wm * 64 + (lane & 15)) * 32 + (lane >> 4) * 8;
    const int brow = (wn * 64 + (lane & 15)) * 32 + (lane >> 4) * 8;

    for (int k0 = 0; k0 < K; k0 += 32) {
        llds16(pa, la);
        llds16(pa + 16 * lda, la + 512);
        llds16(pb, lb);
        llds16(pb + 16 * ldb, lb + 512);
        pa += 32; pb += 32;
        __syncthreads();
        bf16x8 af[4], bg[4];
#pragma unroll
        for (int mt = 0; mt < 4; mt++) af[mt] = *(const bf16x8*)(As + arow + mt * 512);
#pragma unroll
        for (int nt = 0; nt < 4; nt++) bg[nt] = *(const bf16x8*)(Bs + brow + nt * 512);
#pragma unroll
        for (int mt = 0; mt < 4; mt++)
#pragma unroll
            for (int nt = 0; nt < 4; nt++)
                acc[mt][nt] = __builtin_amdgcn_mfma_f32_16x16x32_bf16(af[mt], bg[nt], acc[mt][nt], 0, 0, 0);
        __syncthreads();
    }
}

// ---------------------------------------------------------------------------
// fp32 -> bf16 bulk convert (hidden_states -> Xbf). n multiple of 2048.
// ---------------------------------------------------------------------------
__global__ __launch_bounds__(256) void k_cvt(const float* __restrict__ src, u16* __restrict__ dst) {
    size_t i = ((size_t)blockIdx.x * 256 + threadIdx.x) * 8;
    float4 a = *(const float4*)(src + i);
    float4 b = *(const float4*)(src + i + 4);
    union { u16 h[8]; uint4 v; } o;
    o.h[0] = f2bf(a.x); o.h[1] = f2bf(a.y); o.h[2] = f2bf(a.z); o.h[3] = f2bf(a.w);
    o.h[4] = f2bf(b.x); o.h[5] = f2bf(b.y); o.h[6] = f2bf(b.z); o.h[7] = f2bf(b.w);
    *(uint4*)(dst + i) = o.v;
}

// ---------------------------------------------------------------------------
// Weight transposes + fp32->bf16: W[k][n] fp32 -> Wt[n][k] bf16
// ---------------------------------------------------------------------------
__global__ __launch_bounds__(256) void k_transpose(const float* Wq, const float* Wk, const float* Wv,
                                                   const float* Wo, const float* Wf1, const float* Wf2,
                                                   u16* Wqkv_t, u16* Wo_t, u16* Wf1_t, u16* Wf2_t) {
    const float* src; u16* dst; int R, C;
    switch (blockIdx.z) {
        case 0: src = Wq;  dst = Wqkv_t;                R = 2048; C = 2048; break;
        case 1: src = Wk;  dst = Wqkv_t + 2048 * 2048;  R = 2048; C = 2048; break;
        case 2: src = Wv;  dst = Wqkv_t + 2 * 2048 * 2048; R = 2048; C = 2048; break;
        case 3: src = Wo;  dst = Wo_t;                  R = 2048; C = 2048; break;
        case 4: src = Wf1; dst = Wf1_t;                 R = 128;  C = 256;  break;
        default: src = Wf2; dst = Wf2_t;                R = 256;  C = 256;  break;
    }
    int c0 = blockIdx.x * 32, r0 = blockIdx.y * 32;
    if (c0 >= C || r0 >= R) return;
    __shared__ u16 tile[32][33];
    int tx = threadIdx.x, ty = threadIdx.y;
    for (int i = ty; i < 32; i += 8) tile[i][tx] = f2bf(src[(size_t)(r0 + i) * C + c0 + tx]);
    __syncthreads();
    for (int i = ty; i < 32; i += 8) dst[(size_t)(c0 + i) * R + r0 + tx] = tile[tx][i];
}

// ---------------------------------------------------------------------------
// QKV gemm: Xbf[8192,2048] @ Wqkv_t[6144,2048]^T + bias ->
//   q,k : [bh][l][d]   vT : [bh][d][l]
// LDS-bounce epilogue: C-tile staged in LDS (ld=132), coalesced 16B stores.
// XCD swizzle: 8 consecutive bids share one n-block (W hot per XCD L2).
// ---------------------------------------------------------------------------
__global__ __launch_bounds__(256) void k_gemm_qkv(const u16* __restrict__ X, const u16* __restrict__ Wt,
                                                  const float* __restrict__ bq, const float* __restrict__ bk,
                                                  const float* __restrict__ bv,
                                                  u16* __restrict__ qb, u16* __restrict__ kb, u16* __restrict__ vT) {
    __shared__ u16 S[128 * 132];   // 33792 B; first 8192 u16 = As/Bs in mainloop
    f32x4 acc[4][4];
    const int bid = blockIdx.y * 64 + blockIdx.x;          // 3072
    const int mblk = (bid / 384) * 8 + (bid & 7);          // 64 m-blocks
    const int nblk = (bid >> 3) % 48;                      // 48 n-blocks
    const int mb = mblk * 128, nb = nblk * 128;
    gemm_mainloop(X + (size_t)mb * HS_, HS_, Wt + (size_t)nb * HS_, HS_, HS_, S, S + 4096, acc);
    const int tid = threadIdx.x, lane = tid & 63, wave = tid >> 6;
    const int wm = wave >> 1, wn = wave & 1;
    const int which = nb >> 11;
    const int col0 = nb & 2047;
    const int h = col0 >> 7;
    const int b = mb >> 12;
    const int lb = mb & 4095;
    const int bh = b * NH_ + h;
    const float* bias = (which == 0) ? bq : (which == 1 ? bk : bv);
    const int mloc = wm * 64 + ((lane >> 4) << 2);
    const int nloc = wn * 64 + (lane & 15);
    // phase 1: regs -> LDS (v transposed in-LDS)
    if (which < 2) {
#pragma unroll
        for (int nt = 0; nt < 4; nt++) {
            float bvv = bias[col0 + nloc + nt * 16];
#pragma unroll
            for (int mt = 0; mt < 4; mt++)
#pragma unroll
                for (int r = 0; r < 4; r++)
                    S[(mloc + mt * 16 + r) * 132 + nloc + nt * 16] = f2bf(acc[mt][nt][r] + bvv);
        }
    } else {
#pragma unroll
        for (int nt = 0; nt < 4; nt++) {
            float bvv = bias[col0 + nloc + nt * 16];
#pragma unroll
            for (int mt = 0; mt < 4; mt++)
#pragma unroll
                for (int r = 0; r < 4; r++)
                    S[(nloc + nt * 16) * 132 + mloc + mt * 16 + r] = f2bf(acc[mt][nt][r] + bvv);
        }
    }
    __syncthreads();
    // phase 2: coalesced 16B stores
    u16* dst = (which == 0) ? qb : (which == 1 ? kb : vT);
    const int c8 = (tid & 15) * 8;
#pragma unroll
    for (int it = 0; it < 8; it++) {
        int row = (tid >> 4) + it * 16;
        uint2 lo = *(const uint2*)(S + row * 132 + c8);
        uint2 hi = *(const uint2*)(S + row * 132 + c8 + 4);
        uint4 val = make_uint4(lo.x, lo.y, hi.x, hi.y);
        u16* p = (which < 2) ? dst + ((size_t)bh * L_ + lb + row) * HD_ + c8
                             : dst + ((size_t)bh * HD_ + row) * L_ + lb + c8;
        *(uint4*)p = val;
    }
}

// ---------------------------------------------------------------------------
// Fused feature map (unchanged core). TRANS=1 additionally emits per-block
// ksum partials (removes the separate 67MB k_ksum pass).
// ---------------------------------------------------------------------------
template <int MASKED, int TRANS>
__global__ __launch_bounds__(256) void k_feat(const u16* __restrict__ X,
                                              const u16* __restrict__ W1t, const float* __restrict__ b1,
                                              const u16* __restrict__ W2t, const float* __restrict__ b2,
                                              const float* __restrict__ g, const float* __restrict__ be,
                                              const float* __restrict__ mask,
                                              u16* __restrict__ feat, float* __restrict__ ksp) {
    __shared__ u16 As[64 * 32];
    __shared__ u16 Bs[256 * 32];
    __shared__ u16 H[64 * 264];
    __shared__ float MU[64], RS[64], FAC[64];
    const int tid = threadIdx.x, lane = tid & 63, wave = tid >> 6;
    const int mb = blockIdx.x * 64;

    const int srow = lane >> 2, scol = (lane & 3) * 8;
    const int arow_rd = (lane & 15);
    const int kgrp = (lane >> 4) * 8;

    f32x4 acc[4][4];
    f32x4 zero = {0.f, 0.f, 0.f, 0.f};
#pragma unroll
    for (int i = 0; i < 4; i++)
#pragma unroll
        for (int j = 0; j < 4; j++) acc[i][j] = zero;

    // ---- GEMM1: x[64,128] @ W1t[256,128]^T ----
    for (int k0 = 0; k0 < 128; k0 += 32) {
        llds16(X + (size_t)(mb + wave * 16 + srow) * 128 + k0 + scol, As + wave * 512);
#pragma unroll
        for (int i = 0; i < 4; i++)
            llds16(W1t + (size_t)((wave * 4 + i) * 16 + srow) * 128 + k0 + scol,
                   Bs + (wave * 4 + i) * 512);
        __syncthreads();
        bf16x8 af[4], bg[4];
#pragma unroll
        for (int mt = 0; mt < 4; mt++) af[mt] = *(const bf16x8*)(As + (mt * 16 + arow_rd) * 32 + kgrp);
#pragma unroll
        for (int nt = 0; nt < 4; nt++) bg[nt] = *(const bf16x8*)(Bs + (wave * 64 + nt * 16 + arow_rd) * 32 + kgrp);
#pragma unroll
        for (int mt = 0; mt < 4; mt++)
#pragma unroll
            for (int nt = 0; nt < 4; nt++)
                acc[mt][nt] = __builtin_amdgcn_mfma_f32_16x16x32_bf16(af[mt], bg[nt], acc[mt][nt], 0, 0, 0);
        __syncthreads();
    }
    {
        const int rbase = (lane >> 4) << 2;
#pragma unroll
        for (int nt = 0; nt < 4; nt++) {
            int n = wave * 64 + nt * 16 + (lane & 15);
            float bvv = b1[n];
#pragma unroll
            for (int mt = 0; mt < 4; mt++)
#pragma unroll
                for (int r = 0; r < 4; r++) {
                    float v = fmaxf(acc[mt][nt][r] + bvv, 0.f);
                    H[(mt * 16 + rbase + r) * 264 + n] = f2bf(v);
                }
            acc[0][nt] = zero; acc[1][nt] = zero; acc[2][nt] = zero; acc[3][nt] = zero;
        }
    }
    __syncthreads();

    // ---- GEMM2: h1[64,256] @ W2t[256,256]^T ----
    for (int k0 = 0; k0 < 256; k0 += 32) {
#pragma unroll
        for (int i = 0; i < 4; i++)
            llds16(W2t + (size_t)((wave * 4 + i) * 16 + srow) * 256 + k0 + scol,
                   Bs + (wave * 4 + i) * 512);
        __syncthreads();
        bf16x8 af[4], bg[4];
#pragma unroll
        for (int mt = 0; mt < 4; mt++) af[mt] = *(const bf16x8*)(H + (mt * 16 + arow_rd) * 264 + k0 + kgrp);
#pragma unroll
        for (int nt = 0; nt < 4; nt++) bg[nt] = *(const bf16x8*)(Bs + (wave * 64 + nt * 16 + arow_rd) * 32 + kgrp);
#pragma unroll
        for (int mt = 0; mt < 4; mt++)
#pragma unroll
            for (int nt = 0; nt < 4; nt++)
                acc[mt][nt] = __builtin_amdgcn_mfma_f32_16x16x32_bf16(af[mt], bg[nt], acc[mt][nt], 0, 0, 0);
        __syncthreads();
    }
    {
        const int rbase = (lane >> 4) << 2;
#pragma unroll
        for (int nt = 0; nt < 4; nt++) {
            int n = wave * 64 + nt * 16 + (lane & 15);
            float bvv = b2[n];
#pragma unroll
            for (int mt = 0; mt < 4; mt++)
#pragma unroll
                for (int r = 0; r < 4; r++)
                    H[(mt * 16 + rbase + r) * 264 + n] = f2bf(acc[mt][nt][r] + bvv);
        }
    }
    __syncthreads();

    // ---- LayerNorm stats ----
    {
        for (int r = 0; r < 16; r++) {
            int row = wave * 16 + r;
            int j = lane * 4;
            uint2 u = *(const uint2*)(H + row * 264 + j);
            float x0 = bf2f((u16)(u.x & 0xffff)), x1 = bf2f((u16)(u.x >> 16));
            float x2 = bf2f((u16)(u.y & 0xffff)), x3 = bf2f((u16)(u.y >> 16));
            float s = x0 + x1 + x2 + x3;
            float ss = x0 * x0 + x1 * x1 + x2 * x2 + x3 * x3;
#pragma unroll
            for (int o = 32; o >= 1; o >>= 1) { s += __shfl_xor(s, o); ss += __shfl_xor(ss, o); }
            if (lane == 0) {
                float mu = s * (1.f / FD_);
                float var = ss * (1.f / FD_) - mu * mu;
                MU[row] = mu;
                RS[row] = rsqrtf(var + 1e-5f);
                float fac = 1.f;
                if (MASKED) {
                    int grow = mb + row;
                    int b = grow >> 16;
                    int l = grow & 4095;
                    fac = 1.f + mask[b * L_ + l];
                }
                FAC[row] = fac;
            }
        }
    }
    __syncthreads();

    if (!TRANS) {
        int j = lane * 4;
        float4 gg = *(const float4*)(g + j);
        float4 bb = *(const float4*)(be + j);
        for (int r = 0; r < 16; r++) {
            int row = wave * 16 + r;
            float mu = MU[row], rstd = RS[row], fac = FAC[row];
            uint2 u = *(const uint2*)(H + row * 264 + j);
            float x0 = bf2f((u16)(u.x & 0xffff)), x1 = bf2f((u16)(u.x >> 16));
            float x2 = bf2f((u16)(u.y & 0xffff)), x3 = bf2f((u16)(u.y >> 16));
            uint2 o2;
            o2.x = (u32)f2bf(((x0 - mu) * rstd * gg.x + bb.x) * fac) |
                   ((u32)f2bf(((x1 - mu) * rstd * gg.y + bb.y) * fac) << 16);
            o2.y = (u32)f2bf(((x2 - mu) * rstd * gg.z + bb.z) * fac) |
                   ((u32)f2bf(((x3 - mu) * rstd * gg.w + bb.w) * fac) << 16);
            *(uint2*)(feat + (size_t)(mb + row) * FD_ + j) = o2;
        }
    } else {
        // write featT[bh][f][l] + ksum partial per (block, f)
        int f = tid;
        int bh = mb >> 12, lb = mb & 4095;
        float gf = g[f], bf = be[f];
        u16* orow = feat + ((size_t)bh * FD_ + f) * L_ + lb;
        float fsum = 0.f;
        for (int lg = 0; lg < 64; lg += 8) {
            union { u16 h8[8]; uint4 v4; } pk;
#pragma unroll
            for (int j = 0; j < 8; j++) {
                int row = lg + j;
                float x = bf2f(H[row * 264 + f]);
                float y = ((x - MU[row]) * RS[row] * gf + bf) * FAC[row];
                fsum += y;
                pk.h8[j] = f2bf(y);
            }
            *(uint4*)(orow + lg) = pk.v4;
        }
        ksp[((size_t)bh * 64 + (lb >> 6)) * FD_ + f] = fsum;
    }
}

// reduce 64 per-block partials -> ksum[bh][f]
__global__ __launch_bounds__(256) void k_ksum2(const float* __restrict__ ksp, float* __restrict__ ksum) {
    const int bh = blockIdx.x, f = threadIdx.x;
    float s = 0.f;
    for (int i = 0; i < 64; i++) s += ksp[((size_t)bh * 64 + i) * FD_ + f];
    ksum[(size_t)bh * FD_ + f] = s;
}

// ---------------------------------------------------------------------------
// kv GEMM: per (f-block, k-slice, bh): kfT[256,4096] @ vT[128,4096]^T
// fp32 partials [ks*32+bh][f][d]; K split 8-way for occupancy (512 blocks)
// ---------------------------------------------------------------------------
__global__ __launch_bounds__(256) void k_gemm_kv(const u16* __restrict__ kfT, const u16* __restrict__ vT,
                                                 float* __restrict__ kvp) {
    __shared__ u16 As[4096], Bs[4096];
    f32x4 acc[4][4];
    const int mb = blockIdx.x * 128;    // f block (0..1)
    const int ks = blockIdx.y;          // k slice (0..7), 512 each
    const int bh = blockIdx.z;
    gemm_mainloop(kfT + ((size_t)bh * FD_ + mb) * L_ + ks * 512, L_,
                  vT + (size_t)bh * HD_ * L_ + ks * 512, L_, 512, As, Bs, acc);
    const int lane = threadIdx.x & 63, wave = threadIdx.x >> 6;
    const int wm = wave >> 1, wn = wave & 1;
    const int n0 = wn * 64 + (lane & 15);
    const int m0 = mb + wm * 64 + ((lane >> 4) << 2);
    float* o = kvp + (size_t)(ks * 32 + bh) * (FD_ * HD_);
#pragma unroll
    for (int nt = 0; nt < 4; nt++)
#pragma unroll
        for (int mt = 0; mt < 4; mt++)
#pragma unroll
            for (int r = 0; r < 4; r++)
                o[(size_t)(m0 + mt * 16 + r) * HD_ + n0 + nt * 16] = acc[mt][nt][r];
}

// reduce 8 k-slice partials -> kvT[bh][d][f] bf16
__global__ __launch_bounds__(256) void k_kvred(const float* __restrict__ kvp, u16* __restrict__ kvT) {
    const int p = blockIdx.x, bh = blockIdx.y, t = threadIdx.x;
    const int e0 = p * 4096 + t * 16;
    float s[16];
#pragma unroll
    for (int i = 0; i < 16; i++) s[i] = 0.f;
    for (int c = 0; c < 8; c++) {
        const float* src = kvp + ((size_t)(c * 32 + bh)) * 32768 + e0;
#pragma unroll
        for (int i = 0; i < 16; i += 4) {
            float4 vv = *(const float4*)(src + i);
            s[i] += vv.x; s[i + 1] += vv.y; s[i + 2] += vv.z; s[i + 3] += vv.w;
        }
    }
#pragma unroll
    for (int i = 0; i < 16; i++) {
        int e = e0 + i, fq = e >> 7, d = e & 127;
        kvT[((size_t)bh * HD_ + d) * FD_ + fq] = f2bf(s[i]);
    }
}

// denom[row] = q_feat[row,:] . k_sum[bh,:]
__global__ __launch_bounds__(256) void k_denom(const u16* __restrict__ qf, const float* __restrict__ ksum,
                                               float* __restrict__ denom) {
    const int lane = threadIdx.x & 63, wave = threadIdx.x >> 6;
    const size_t row = (size_t)blockIdx.x * 4 + wave;
    const int bh = (int)(row >> 12);
    uint2 u = *(const uint2*)(qf + row * FD_ + lane * 4);
    float4 kk = *(const float4*)(ksum + (size_t)bh * FD_ + lane * 4);
    float d = bf2f((u16)(u.x & 0xffff)) * kk.x + bf2f((u16)(u.x >> 16)) * kk.y
            + bf2f((u16)(u.y & 0xffff)) * kk.z + bf2f((u16)(u.y >> 16)) * kk.w;
#pragma unroll
    for (int o = 32; o >= 1; o >>= 1) d += __shfl_xor(d, o);
    if (lane == 0) denom[row] = d;
}

// attn numerator gemm per head + divide; LDS-bounce coalesced bf16 stores
__global__ __launch_bounds__(256) void k_gemm_attn(const u16* __restrict__ qf, const u16* __restrict__ kvT,
                                                   const float* __restrict__ denom, u16* __restrict__ attn) {
    __shared__ u16 S[128 * 132];
    f32x4 acc[4][4];
    const int mb = blockIdx.x * 128;
    const int bh = blockIdx.y;
    gemm_mainloop(qf + ((size_t)bh * L_ + mb) * FD_, FD_, kvT + (size_t)bh * HD_ * FD_, FD_, FD_, S, S + 4096, acc);
    const int tid = threadIdx.x, lane = tid & 63, wave = tid >> 6;
    const int wm = wave >> 1, wn = wave & 1;
    const int b = bh >> 4, h = bh & 15;
    const int mloc = wm * 64 + ((lane >> 4) << 2);
    const int nloc = wn * 64 + (lane & 15);
#pragma unroll
    for (int mt = 0; mt < 4; mt++)
#pragma unroll
        for (int r = 0; r < 4; r++) {
            int l = mb + mloc + mt * 16 + r;
            float rden = 1.f / (denom[(size_t)bh * L_ + l] + 1e-8f);
#pragma unroll
            for (int nt = 0; nt < 4; nt++)
                S[(mloc + mt * 16 + r) * 132 + nloc + nt * 16] = f2bf(acc[mt][nt][r] * rden);
        }
    __syncthreads();
    const int c8 = (tid & 15) * 8;
#pragma unroll
    for (int it = 0; it < 8; it++) {
        int row = (tid >> 4) + it * 16;
        uint2 lo = *(const uint2*)(S + row * 132 + c8);
        uint2 hi = *(const uint2*)(S + row * 132 + c8 + 4);
        uint4 val = make_uint4(lo.x, lo.y, hi.x, hi.y);
        *(uint4*)(attn + ((size_t)(b * L_ + mb + row)) * HS_ + h * HD_ + c8) = val;
    }
}

// final projection: attn[8192,2048] @ Wo_t^T + bo -> d_out (fp32), swizzled
__global__ __launch_bounds__(256) void k_gemm_out(const u16* __restrict__ A, const u16* __restrict__ Wt,
                                                  const float* __restrict__ bo, float* __restrict__ out) {
    __shared__ u16 As[4096], Bs[4096];
    f32x4 acc[4][4];
    const int bid = blockIdx.y * 64 + blockIdx.x;          // 1024
    const int mblk = (bid / 128) * 8 + (bid & 7);          // 64
    const int nblk = (bid >> 3) % 16;                      // 16
    const int mb = mblk * 128, nb = nblk * 128;
    gemm_mainloop(A + (size_t)mb * HS_, HS_, Wt + (size_t)nb * HS_, HS_, HS_, As, Bs, acc);
    const int lane = threadIdx.x & 63, wave = threadIdx.x >> 6;
    const int wm = wave >> 1, wn = wave & 1;
    const int n0 = nb + wn * 64 + (lane & 15);
    const int m0 = mb + wm * 64 + ((lane >> 4) << 2);
#pragma unroll
    for (int nt = 0; nt < 4; nt++) {
        int n = n0 + nt * 16;
        float bvv = bo[n];
#pragma unroll
        for (int mt = 0; mt < 4; mt++)
#pragma unroll
            for (int r = 0; r < 4; r++)
                out[(size_t)(m0 + mt * 16 + r) * HS_ + n] = acc[mt][nt][r] + bvv;
    }
}

// ---------------------------------------------------------------------------
// workspace layout (bytes), total ~237 MiB.
//   [0]          qfeat 67,108,864   (front: Wqkv_t 25,165,824 then Xbf
//                                    33,554,432 — both dead before qfeat)
//   [67108864]   kfT   67,108,864   ([bh][f][l])
//   [134217728]  qbuf  33,554,432   -> kvp (32 MB fp32 partials) after feat<q>
//   [167772160]  kbuf  33,554,432   -> attn after feat<k>
//   [201326592]  vT    33,554,432   ([bh][d][l])
//   [234881024]  Wo_t   8,388,608
//   [243269632]  Wf1_t     65,536
//   [243335168]  Wf2_t    131,072
//   [243466240]  ksp    2,097,152
//   [245563392]  kvT    2,097,152
//   [247660544]  ksum      32,768
//   [247693312]  denom    524,288   -> end 248,217,600
// ---------------------------------------------------------------------------
extern "C" void kernel_launch(void* const* d_in, const int* in_sizes, int n_in,
                              void* d_out, int out_size, void* d_ws, size_t ws_size,
                              hipStream_t stream) {
    const float* hs  = (const float*)d_in[0];
    const float* msk = (const float*)d_in[1];
    const float* Wq  = (const float*)d_in[2];  const float* bq  = (const float*)d_in[3];
    const float* Wk  = (const float*)d_in[4];  const float* bk  = (const float*)d_in[5];
    const float* Wv  = (const float*)d_in[6];  const float* bv  = (const float*)d_in[7];
    const float* Wo  = (const float*)d_in[8];  const float* bo  = (const float*)d_in[9];
    const float* Wf1 = (const float*)d_in[10]; const float* bf1 = (const float*)d_in[11];
    const float* Wf2 = (const float*)d_in[12]; const float* bf2 = (const float*)d_in[13];
    const float* lng = (const float*)d_in[14]; const float* lnb = (const float*)d_in[15];
    float* out = (float*)d_out;
    char* w = (char*)d_ws;

    u16* qfeat  = (u16*)(w + 0);
    u16* Wqkv_t = (u16*)(w + 0);               // alias: dead before qfeat written
    u16* Xbf    = (u16*)(w + 25165824u);       // alias: dead before qfeat written
    u16* kfT    = (u16*)(w + 67108864u);
    u16* qbuf   = (u16*)(w + 134217728u);
    float* kvp  = (float*)(w + 134217728u);    // alias: qbuf dead after k_feat<q>
    u16* kbuf   = (u16*)(w + 167772160u);
    u16* attn   = (u16*)(w + 167772160u);      // alias: kbuf dead after k_feat<k>
    u16* vT     = (u16*)(w + 201326592u);
    u16* Wo_t   = (u16*)(w + 234881024u);
    u16* Wf1_t  = (u16*)(w + 243269632u);
    u16* Wf2_t  = (u16*)(w + 243335168u);
    float* ksp  = (float*)(w + 243466240u);
    u16* kvT    = (u16*)(w + 245563392u);
    float* ksum = (float*)(w + 247660544u);
    float* denom = (float*)(w + 247693312u);

    k_cvt<<<dim3(8192), 256, 0, stream>>>(hs, Xbf);
    k_transpose<<<dim3(64, 64, 6), dim3(32, 8), 0, stream>>>(Wq, Wk, Wv, Wo, Wf1, Wf2,
                                                             Wqkv_t, Wo_t, Wf1_t, Wf2_t);
    k_gemm_qkv<<<dim3(64, 48), 256, 0, stream>>>(Xbf, Wqkv_t, bq, bk, bv, qbuf, kbuf, vT);
    k_feat<0, 0><<<dim3(2048), 256, 0, stream>>>(qbuf, Wf1_t, bf1, Wf2_t, bf2, lng, lnb, msk, qfeat, ksp);
    k_feat<1, 1><<<dim3(2048), 256, 0, stream>>>(kbuf, Wf1_t, bf1, Wf2_t, bf2, lng, lnb, msk, kfT, ksp);
    k_ksum2<<<dim3(32), 256, 0, stream>>>(ksp, ksum);
    k_gemm_kv<<<dim3(2, 8, 32), 256, 0, stream>>>(kfT, vT, kvp);
    k_kvred<<<dim3(8, 32), 256, 0, stream>>>(kvp, kvT);
    k_denom<<<dim3(32768), 256, 0, stream>>>(qfeat, ksum, denom);
    k_gemm_attn<<<dim3(32, 32), 256, 0, stream>>>(qfeat, kvT, denom, attn);
    k_gemm_out<<<dim3(64, 16), 256, 0, stream>>>(attn, Wo_t, bo, out);
}